// Round 1
// baseline (251.821 us; speedup 1.0000x reference)
//
#include <hip/hip_runtime.h>

// Problem dims (fixed)
constexpr int Bb = 2, Nn = 8192, Kk = 16, Cc = 256, Hh = 8;
constexpr int TN = 4;                     // n-positions per block
constexpr float SCALE = 0.17677669529663687f;  // 32^-0.5

typedef __attribute__((ext_vector_type(8))) short bf16x8;
typedef __attribute__((ext_vector_type(4))) float f32x4;

__device__ inline unsigned short f2bf(float f) {
  unsigned u = __float_as_uint(f);
  u = (u + 0x7fffu + ((u >> 16) & 1u)) >> 16;
  return (unsigned short)u;
}
__device__ inline float bf2f(short h) {
  return __uint_as_float(((unsigned)(unsigned short)h) << 16);
}

// ---------------- prep: weights fp32 -> bf16 MFMA-B-fragment layout ----------------
// B[ci][co] = W[co][ci]; frag idx = ((nt*8 + ks)*64 + lane)*8 + j
// co = nt*16 + (lane&15); ci = ks*32 + (lane>>4)*8 + j
__global__ void prep_weights(const float* __restrict__ Wq, const float* __restrict__ Wk,
                             const float* __restrict__ Wv, const float* __restrict__ Wo,
                             short* __restrict__ wsb) {
  int idx = blockIdx.x * 256 + threadIdx.x;   // 0..65535
  int j = idx & 7;
  int lane = (idx >> 3) & 63;
  int ks = (idx >> 9) & 7;
  int nt = idx >> 12;
  int co = nt * 16 + (lane & 15);
  int ci = ks * 32 + (lane >> 4) * 8 + j;
  int src = co * 256 + ci;
  wsb[idx]          = (short)f2bf(Wq[src]);
  wsb[65536 + idx]  = (short)f2bf(Wk[src]);
  wsb[131072 + idx] = (short)f2bf(Wv[src]);
  wsb[196608 + idx] = (short)f2bf(Wo[src]);
}

// LayerNorm a 256-float row held wave-wide (lane has cols lane*4..+3), write bf16x4 to
// swizzled LDS: phys_byte = row*512 + (logical_byte ^ ((row&7)<<4))
__device__ inline void ln_row_store(const float4 v, int row, const float4 g4, const float4 b4,
                                    char* S, int lane) {
  float s  = v.x + v.y + v.z + v.w;
  float ss = fmaf(v.x, v.x, fmaf(v.y, v.y, fmaf(v.z, v.z, v.w * v.w)));
#pragma unroll
  for (int m = 32; m >= 1; m >>= 1) {
    s  += __shfl_xor(s, m, 64);
    ss += __shfl_xor(ss, m, 64);
  }
  float mu   = s * (1.0f / 256.0f);
  float var  = ss * (1.0f / 256.0f) - mu * mu;
  float rstd = rsqrtf(var + 1e-5f);
  ushort4 o;
  o.x = f2bf((v.x - mu) * rstd * g4.x + b4.x);
  o.y = f2bf((v.y - mu) * rstd * g4.y + b4.y);
  o.z = f2bf((v.z - mu) * rstd * g4.z + b4.z);
  o.w = f2bf((v.w - mu) * rstd * g4.w + b4.w);
  *(ushort4*)(S + row * 512 + ((lane * 8) ^ ((row & 7) << 4))) = o;
}

// 64-row x 256-col GEMM from swizzled LDS A vs frag-layout global B, col-split by wave.
__device__ inline void gemm64(const char* S, const short* __restrict__ WB, int wave, int lane,
                              f32x4 acc[4][4]) {
#pragma unroll
  for (int ks = 0; ks < 8; ++ks) {
    bf16x8 bb[4];
#pragma unroll
    for (int ntl = 0; ntl < 4; ++ntl)
      bb[ntl] = *(const bf16x8*)(WB + (((wave * 4 + ntl) * 8 + ks) * 64 + lane) * 8);
#pragma unroll
    for (int mt = 0; mt < 4; ++mt) {
      int row = mt * 16 + (lane & 15);
      bf16x8 a = *(const bf16x8*)(S + row * 512 +
                                  ((ks * 64 + (lane >> 4) * 16) ^ ((row & 7) << 4)));
#pragma unroll
      for (int ntl = 0; ntl < 4; ++ntl)
        acc[mt][ntl] = __builtin_amdgcn_mfma_f32_16x16x32_bf16(a, bb[ntl], acc[mt][ntl], 0, 0, 0);
    }
  }
}

// write projected tile (+bias, bf16) back into S, same swizzle
__device__ inline void write_proj(char* S, const float* __restrict__ bias, int wave, int lane,
                                  f32x4 acc[4][4]) {
#pragma unroll
  for (int ntl = 0; ntl < 4; ++ntl) {
    int c = wave * 64 + ntl * 16 + (lane & 15);
    float bv = bias[c];
#pragma unroll
    for (int mt = 0; mt < 4; ++mt) {
#pragma unroll
      for (int reg = 0; reg < 4; ++reg) {
        int r = mt * 16 + (lane >> 4) * 4 + reg;
        *(unsigned short*)(S + r * 512 + ((c * 2) ^ ((r & 7) << 4))) =
            f2bf(acc[mt][ntl][reg] + bv);
      }
    }
  }
}

__global__ __launch_bounds__(256, 2) void geo_attn_main(
    const float* __restrict__ query, const float* __restrict__ key_,
    const float* __restrict__ value, const float* __restrict__ lnq_g,
    const float* __restrict__ lnq_b, const float* __restrict__ bq,
    const float* __restrict__ lnk_g, const float* __restrict__ lnk_b,
    const float* __restrict__ bk, const float* __restrict__ lnv_g,
    const float* __restrict__ lnv_b, const float* __restrict__ bv,
    const float* __restrict__ bo, const short* __restrict__ wsb, float* __restrict__ out) {
  __shared__ char smem[45056];
  char* S  = smem;           // [64][512B]  staging -> kproj -> staging -> vproj (swizzled)
  char* PR = smem + 32768;   // [16][32] f32 probs (layout probs[k][g], g = nl*8+h)
  char* AT = smem + 34816;   // [16][512B]  q-stage, later attn_out (rows>=TN stay zero)
  char* QL = smem + 43008;   // [4][512B]   q_proj bf16, plain layout

  const int tid = threadIdx.x;
  const int lane = tid & 63;
  const int wave = tid >> 6;
  const int blk = blockIdx.x;
  const int b = blk >> 11;
  const int n0 = (blk & 2047) * TN;

  const short* WqB = wsb;
  const short* WkB = wsb + 65536;
  const short* WvB = wsb + 131072;
  const short* WoB = wsb + 196608;

  // ---- Phase 1: q-stage into AT (16 rows; rows >= TN zeroed) ----
  {
    float4 g4 = *(const float4*)(lnq_g + lane * 4);
    float4 b4 = *(const float4*)(lnq_b + lane * 4);
#pragma unroll
    for (int i = 0; i < 4; ++i) {
      int row = i * 4 + wave;
      if (row < TN) {
        float4 v = *(const float4*)(query + (size_t)(b * Nn + n0 + row) * 256 + lane * 4);
        ln_row_store(v, row, g4, b4, AT, lane);
      } else {
        ushort4 z = {0, 0, 0, 0};
        *(ushort4*)(AT + row * 512 + ((lane * 8) ^ ((row & 7) << 4))) = z;
      }
    }
  }
  __syncthreads();

  // ---- Phase 2: q-proj mini-GEMM -> QL ----
  {
    f32x4 qacc[4] = {};
#pragma unroll
    for (int ks = 0; ks < 8; ++ks) {
      int arow = lane & 15;
      bf16x8 a = *(const bf16x8*)(AT + arow * 512 +
                                  ((ks * 64 + (lane >> 4) * 16) ^ ((arow & 7) << 4)));
#pragma unroll
      for (int ntl = 0; ntl < 4; ++ntl) {
        bf16x8 bb = *(const bf16x8*)(WqB + (((wave * 4 + ntl) * 8 + ks) * 64 + lane) * 8);
        qacc[ntl] = __builtin_amdgcn_mfma_f32_16x16x32_bf16(a, bb, qacc[ntl], 0, 0, 0);
      }
    }
    if ((lane >> 4) == 0) {
#pragma unroll
      for (int ntl = 0; ntl < 4; ++ntl) {
        int c = wave * 64 + ntl * 16 + (lane & 15);
        float bqv = bq[c];
#pragma unroll
        for (int reg = 0; reg < 4; ++reg)
          *(unsigned short*)(QL + reg * 512 + c * 2) = f2bf(qacc[ntl][reg] + bqv);
      }
    }
  }

  // ---- Phase 3: K-stage into S (64 rows), 16 loads in flight per wave ----
  {
    float4 g4 = *(const float4*)(lnk_g + lane * 4);
    float4 b4 = *(const float4*)(lnk_b + lane * 4);
    const float* src = key_ + (size_t)((b * Nn + n0) * 16) * 256;
    int rbase = wave * 16;
    float4 buf[2][8];
#pragma unroll
    for (int i = 0; i < 8; ++i)
      buf[0][i] = *(const float4*)(src + (size_t)(rbase + i) * 256 + lane * 4);
#pragma unroll
    for (int i = 0; i < 8; ++i)
      buf[1][i] = *(const float4*)(src + (size_t)(rbase + 8 + i) * 256 + lane * 4);
#pragma unroll
    for (int i = 0; i < 8; ++i) ln_row_store(buf[0][i], rbase + i, g4, b4, S, lane);
#pragma unroll
    for (int i = 0; i < 8; ++i) ln_row_store(buf[1][i], rbase + 8 + i, g4, b4, S, lane);
  }
  __syncthreads();

  // ---- Phase 4: K-proj GEMM ----
  f32x4 acc[4][4] = {};
  gemm64(S, WkB, wave, lane, acc);
  __syncthreads();   // all waves done reading staged K
  write_proj(S, bk, wave, lane, acc);
  __syncthreads();

  // ---- Phase 5: logits (q . k) * SCALE -> PR ----
  {
    int g = tid >> 3;         // 0..31
    int nl = g >> 3, h = g & 7;
    int kb = (tid & 7) * 2;
    float qv[32];
#pragma unroll
    for (int j4 = 0; j4 < 4; ++j4) {
      bf16x8 qq = *(const bf16x8*)(QL + nl * 512 + h * 64 + j4 * 16);
#pragma unroll
      for (int j = 0; j < 8; ++j) qv[j4 * 8 + j] = bf2f(qq[j]);
    }
#pragma unroll
    for (int kk = 0; kk < 2; ++kk) {
      int k = kb + kk;
      int row = nl * 16 + k;
      float a = 0.f;
#pragma unroll
      for (int j4 = 0; j4 < 4; ++j4) {
        bf16x8 kv = *(const bf16x8*)(S + row * 512 +
                                     ((h * 64 + j4 * 16) ^ ((row & 7) << 4)));
#pragma unroll
        for (int j = 0; j < 8; ++j) a = fmaf(qv[j4 * 8 + j], bf2f(kv[j]), a);
      }
      *(float*)(PR + (k * 32 + g) * 4) = a * SCALE;
    }
  }
  __syncthreads();

  // ---- Phase 6: softmax (32 threads) ----
  if (tid < 32) {
    float p[16];
#pragma unroll
    for (int k = 0; k < 16; ++k) p[k] = *(const float*)(PR + (k * 32 + tid) * 4);
    float m = p[0];
#pragma unroll
    for (int k = 1; k < 16; ++k) m = fmaxf(m, p[k]);
    float ssum = 0.f;
#pragma unroll
    for (int k = 0; k < 16; ++k) { p[k] = __expf(p[k] - m); ssum += p[k]; }
    float inv = 1.0f / ssum;
#pragma unroll
    for (int k = 0; k < 16; ++k) *(float*)(PR + (k * 32 + tid) * 4) = p[k] * inv;
  }

  // ---- Phase 7: V-stage into S ----
  {
    float4 g4 = *(const float4*)(lnv_g + lane * 4);
    float4 b4 = *(const float4*)(lnv_b + lane * 4);
    const float* src = value + (size_t)((b * Nn + n0) * 16) * 256;
    int rbase = wave * 16;
    float4 buf[2][8];
#pragma unroll
    for (int i = 0; i < 8; ++i)
      buf[0][i] = *(const float4*)(src + (size_t)(rbase + i) * 256 + lane * 4);
#pragma unroll
    for (int i = 0; i < 8; ++i)
      buf[1][i] = *(const float4*)(src + (size_t)(rbase + 8 + i) * 256 + lane * 4);
#pragma unroll
    for (int i = 0; i < 8; ++i) ln_row_store(buf[0][i], rbase + i, g4, b4, S, lane);
#pragma unroll
    for (int i = 0; i < 8; ++i) ln_row_store(buf[1][i], rbase + 8 + i, g4, b4, S, lane);
  }
  __syncthreads();

  // ---- Phase 8: V-proj GEMM ----
#pragma unroll
  for (int mt = 0; mt < 4; ++mt)
#pragma unroll
    for (int ntl = 0; ntl < 4; ++ntl) acc[mt][ntl] = (f32x4){0.f, 0.f, 0.f, 0.f};
  gemm64(S, WvB, wave, lane, acc);
  __syncthreads();
  write_proj(S, bv, wave, lane, acc);
  __syncthreads();

  // ---- Phase 9: PV -> AT rows 0..TN-1 ----
  {
    int nl = tid >> 6;              // == wave
    int c0 = (tid & 63) * 4;
    int h = c0 >> 5;
    float o0 = 0.f, o1 = 0.f, o2 = 0.f, o3 = 0.f;
#pragma unroll
    for (int k = 0; k < 16; ++k) {
      float p = *(const float*)(PR + (k * 32 + nl * 8 + h) * 4);
      int row = nl * 16 + k;
      ushort4 vv = *(const ushort4*)(S + row * 512 + ((c0 * 2) ^ ((row & 7) << 4)));
      o0 = fmaf(p, bf2f((short)vv.x), o0);
      o1 = fmaf(p, bf2f((short)vv.y), o1);
      o2 = fmaf(p, bf2f((short)vv.z), o2);
      o3 = fmaf(p, bf2f((short)vv.w), o3);
    }
    ushort4 ob;
    ob.x = f2bf(o0); ob.y = f2bf(o1); ob.z = f2bf(o2); ob.w = f2bf(o3);
    *(ushort4*)(AT + nl * 512 + ((c0 * 2) ^ ((nl & 7) << 4))) = ob;
  }
  __syncthreads();

  // ---- Phase 10: out-proj GEMM + store ----
  {
    f32x4 oacc[4] = {};
#pragma unroll
    for (int ks = 0; ks < 8; ++ks) {
      int arow = lane & 15;
      bf16x8 a = *(const bf16x8*)(AT + arow * 512 +
                                  ((ks * 64 + (lane >> 4) * 16) ^ ((arow & 7) << 4)));
#pragma unroll
      for (int ntl = 0; ntl < 4; ++ntl) {
        bf16x8 bb = *(const bf16x8*)(WoB + (((wave * 4 + ntl) * 8 + ks) * 64 + lane) * 8);
        oacc[ntl] = __builtin_amdgcn_mfma_f32_16x16x32_bf16(a, bb, oacc[ntl], 0, 0, 0);
      }
    }
    if ((lane >> 4) == 0) {
#pragma unroll
      for (int ntl = 0; ntl < 4; ++ntl) {
        int c = wave * 64 + ntl * 16 + (lane & 15);
        float bov = bo[c];
#pragma unroll
        for (int reg = 0; reg < 4; ++reg)
          out[(size_t)(b * Nn + n0 + reg) * 256 + c] = oacc[ntl][reg] + bov;
      }
    }
  }
}

extern "C" void kernel_launch(void* const* d_in, const int* in_sizes, int n_in,
                              void* d_out, int out_size, void* d_ws, size_t ws_size,
                              hipStream_t stream) {
  const float* query = (const float*)d_in[0];
  const float* key_  = (const float*)d_in[1];
  const float* value = (const float*)d_in[2];
  const float* lnq_g = (const float*)d_in[3];
  const float* lnq_b = (const float*)d_in[4];
  const float* Wq    = (const float*)d_in[5];
  const float* bq    = (const float*)d_in[6];
  const float* lnk_g = (const float*)d_in[7];
  const float* lnk_b = (const float*)d_in[8];
  const float* Wk    = (const float*)d_in[9];
  const float* bk    = (const float*)d_in[10];
  const float* lnv_g = (const float*)d_in[11];
  const float* lnv_b = (const float*)d_in[12];
  const float* Wv    = (const float*)d_in[13];
  const float* bv    = (const float*)d_in[14];
  const float* Wo    = (const float*)d_in[15];
  const float* bo    = (const float*)d_in[16];
  short* wsb = (short*)d_ws;
  float* out = (float*)d_out;

  hipLaunchKernelGGL(prep_weights, dim3(256), dim3(256), 0, stream, Wq, Wk, Wv, Wo, wsb);
  hipLaunchKernelGGL(geo_attn_main, dim3(Bb * (Nn / TN)), dim3(256), 0, stream,
                     query, key_, value, lnq_g, lnq_b, bq, lnk_g, lnk_b, bk,
                     lnv_g, lnv_b, bv, bo, wsb, out);
}